// Round 14
// baseline (179.033 us; speedup 1.0000x reference)
//
#include <hip/hip_runtime.h>

#define Bsz 256
#define Dd  4096
#define MAXR 15
#define FMAX 3.402823466e+38f
#define BK 64
#define LSTRIDE 72              // 9 granules (odd): conflict-free phases, 16B-aligned rows

typedef short bf16x8 __attribute__((ext_vector_type(8)));
typedef float f32x4  __attribute__((ext_vector_type(4)));

__device__ __forceinline__ unsigned short f2bf(float f) {
    unsigned int u = __float_as_uint(f);
    unsigned int r = (u + 0x7fffu + ((u >> 16) & 1u)) >> 16;   // RNE
    return (unsigned short)r;
}
__device__ __forceinline__ float bf2f(unsigned short h) {
    return __uint_as_float(((unsigned int)h) << 16);
}

// ---- Kernel 1: S = 0.5*(W+W^T) -> bf16 hi/lo (triangle-paired) + fused x->bf16 ----
__global__ __launch_bounds__(256) void k_ssym(const float* __restrict__ W,
                                              const float* __restrict__ x,
                                              unsigned short* __restrict__ shi,
                                              unsigned short* __restrict__ slo,
                                              unsigned short* __restrict__ xb) {
    __shared__ float t1[64][68];
    __shared__ float t2[64][68];
    int bid = blockIdx.x;
    int bi = 0;
    while (bid >= 64 - bi) { bid -= 64 - bi; ++bi; }
    const int bj = bi + bid;
    const int i0 = bi * 64, j0 = bj * 64;
    const int tid = threadIdx.x;

    #pragma unroll
    for (int sb = 0; sb < 4; ++sb) {
        int s = sb * 256 + tid;
        int r = s >> 4, q = (s & 15) * 4;
        *(float4*)&t1[r][q] = *(const float4*)(W + (size_t)(i0 + r) * Dd + j0 + q);
        *(float4*)&t2[r][q] = *(const float4*)(W + (size_t)(j0 + r) * Dd + i0 + q);
    }
    __syncthreads();

    const int r = tid >> 2, c0 = (tid & 3) * 16;
    {   // S_ij[r][c] = 0.5*(t1[r][c] + t2[c][r])
        unsigned short vh[16], vl[16];
        #pragma unroll
        for (int k = 0; k < 16; ++k) {
            float s = 0.5f * (t1[r][c0 + k] + t2[c0 + k][r]);
            vh[k] = f2bf(s);
            vl[k] = f2bf(s - bf2f(vh[k]));
        }
        size_t o = (size_t)(i0 + r) * Dd + j0 + c0;
        *(uint4*)(shi + o) = *(const uint4*)&vh[0];
        *(uint4*)(shi + o + 8) = *(const uint4*)&vh[8];
        *(uint4*)(slo + o) = *(const uint4*)&vl[0];
        *(uint4*)(slo + o + 8) = *(const uint4*)&vl[8];
    }
    if (bi != bj) {   // S_ji[r][c] = 0.5*(t2[r][c] + t1[c][r])
        unsigned short vh[16], vl[16];
        #pragma unroll
        for (int k = 0; k < 16; ++k) {
            float s = 0.5f * (t2[r][c0 + k] + t1[c0 + k][r]);
            vh[k] = f2bf(s);
            vl[k] = f2bf(s - bf2f(vh[k]));
        }
        size_t o = (size_t)(j0 + r) * Dd + i0 + c0;
        *(uint4*)(shi + o) = *(const uint4*)&vh[0];
        *(uint4*)(shi + o + 8) = *(const uint4*)&vh[8];
        *(uint4*)(slo + o) = *(const uint4*)&vl[0];
        *(uint4*)(slo + o + 8) = *(const uint4*)&vl[8];
    }

    if (blockIdx.x < 256) {
        const float* xp = x + (size_t)blockIdx.x * 4096;
        unsigned short* xo = xb + (size_t)blockIdx.x * 4096;
        #pragma unroll
        for (int c = 0; c < 4; ++c) {
            int e = c * 1024 + tid * 4;
            float4 v = *(const float4*)(xp + e);
            unsigned short o4[4] = { f2bf(v.x), f2bf(v.y), f2bf(v.z), f2bf(v.w) };
            *(uint2*)(xo + e) = *(const uint2*)o4;
        }
    }
}

// ---- Kernel 2: part[z] = X @ S(K-chunk z); single-buffer + VGPR prefetch ----
__global__ __launch_bounds__(128) void k_gemm(const unsigned short* __restrict__ xb,
                                              const unsigned short* __restrict__ shi,
                                              const unsigned short* __restrict__ slo,
                                              float* __restrict__ part,
                                              int kchunk) {
    __shared__ __align__(16) unsigned short As[64 * LSTRIDE];
    __shared__ __align__(16) unsigned short Bh[64 * LSTRIDE];
    __shared__ __align__(16) unsigned short Bl[64 * LSTRIDE];
    const int tid = threadIdx.x;
    const int n0 = blockIdx.x * 64, m0 = blockIdx.y * 64;
    const int kbase = blockIdx.z * kchunk;
    const int w = tid >> 6, lane = tid & 63;
    const int ln = lane & 15, quad = lane >> 4;

    unsigned ga[4], gb[4];
    int lofs[4];
    #pragma unroll
    for (int j = 0; j < 4; ++j) {
        int s = tid + j * 128;
        int r = s >> 3, g = s & 7;
        ga[j]   = (unsigned)((m0 + r) * Dd + kbase + g * 8);
        gb[j]   = (unsigned)((n0 + r) * Dd + kbase + g * 8);
        lofs[j] = r * LSTRIDE + g * 8;
    }

    f32x4 acc[4][2];
    #pragma unroll
    for (int mt = 0; mt < 4; ++mt)
        #pragma unroll
        for (int ct = 0; ct < 2; ++ct)
            #pragma unroll
            for (int rr = 0; rr < 4; ++rr) acc[mt][ct][rr] = 0.0f;

    bf16x8 va[4], vh[4], vl[4];
    #pragma unroll
    for (int j = 0; j < 4; ++j) {
        va[j] = *(const bf16x8*)(xb  + ga[j]);
        vh[j] = *(const bf16x8*)(shi + gb[j]);
        vl[j] = *(const bf16x8*)(slo + gb[j]);
    }

    for (int k0 = 0; k0 < kchunk; k0 += BK) {
        __syncthreads();
        #pragma unroll
        for (int j = 0; j < 4; ++j) {
            *(bf16x8*)&As[lofs[j]] = va[j];
            *(bf16x8*)&Bh[lofs[j]] = vh[j];
            *(bf16x8*)&Bl[lofs[j]] = vl[j];
        }
        {
            int kn = k0 + BK;
            int ks = (kn < kchunk) ? kn : 0;
            #pragma unroll
            for (int j = 0; j < 4; ++j) {
                va[j] = *(const bf16x8*)(xb  + ga[j] + ks);
                vh[j] = *(const bf16x8*)(shi + gb[j] + ks);
                vl[j] = *(const bf16x8*)(slo + gb[j] + ks);
            }
        }
        __syncthreads();
        #pragma unroll
        for (int kk = 0; kk < BK; kk += 32) {
            const int gr = (kk >> 3) + quad;
            bf16x8 a[4];
            #pragma unroll
            for (int mt = 0; mt < 4; ++mt)
                a[mt] = *(const bf16x8*)&As[(mt * 16 + ln) * LSTRIDE + gr * 8];
            #pragma unroll
            for (int ct = 0; ct < 2; ++ct) {
                int rb = w * 32 + ct * 16 + ln;
                bf16x8 bh = *(const bf16x8*)&Bh[rb * LSTRIDE + gr * 8];
                bf16x8 bl = *(const bf16x8*)&Bl[rb * LSTRIDE + gr * 8];
                #pragma unroll
                for (int mt = 0; mt < 4; ++mt) {
                    acc[mt][ct] = __builtin_amdgcn_mfma_f32_16x16x32_bf16(a[mt], bh, acc[mt][ct], 0, 0, 0);
                    acc[mt][ct] = __builtin_amdgcn_mfma_f32_16x16x32_bf16(a[mt], bl, acc[mt][ct], 0, 0, 0);
                }
            }
        }
    }
    float* prow = part + (size_t)blockIdx.z * (Bsz * Dd);
    #pragma unroll
    for (int mt = 0; mt < 4; ++mt)
        #pragma unroll
        for (int ct = 0; ct < 2; ++ct)
            #pragma unroll
            for (int rr = 0; rr < 4; ++rr) {
                int m = m0 + mt * 16 + quad * 4 + rr;
                int n = n0 + w * 32 + ct * 16 + ln;
                prow[(size_t)m * Dd + n] = acc[mt][ct][rr];
            }
}

// ---- Kernel 3a: wide phase-1 — grad/sc/key + out=x + per-64-chunk stats ----
// grid 1024 (4 blocks/row); BW-shaped: each thread 4 elems, 7 loads + 3 stores.
__global__ __launch_bounds__(256) void k_phase1(const float* __restrict__ x,
                                                const float* __restrict__ gu,
                                                const float* __restrict__ part,
                                                const float* __restrict__ bias,
                                                float* __restrict__ out,
                                                float* __restrict__ key_ws,
                                                float* __restrict__ sc_ws,
                                                float* __restrict__ kmax_ws,
                                                int*   __restrict__ kidx_ws,
                                                float* __restrict__ smax_ws,
                                                float* __restrict__ ssum_ws,
                                                int nsplit) {
    const int b = blockIdx.x >> 2, qd = blockIdx.x & 3;
    const int tid = threadIdx.x;
    const int j0 = qd * 1024 + tid * 4;
    const size_t row = (size_t)b * Dd;

    float4 g4 = *(const float4*)(part + row + j0);                 // z = 0
    if (nsplit == 4) {
        float4 p1 = *(const float4*)(part + (size_t)(1 * Bsz + b) * Dd + j0);
        float4 p2 = *(const float4*)(part + (size_t)(2 * Bsz + b) * Dd + j0);
        float4 p3 = *(const float4*)(part + (size_t)(3 * Bsz + b) * Dd + j0);
        g4.x = ((g4.x + p1.x) + p2.x) + p3.x;
        g4.y = ((g4.y + p1.y) + p2.y) + p3.y;
        g4.z = ((g4.z + p1.z) + p2.z) + p3.z;
        g4.w = ((g4.w + p1.w) + p2.w) + p3.w;
    } else {
        for (int z = 1; z < nsplit; ++z) {
            float4 a = *(const float4*)(part + (size_t)(z * Bsz + b) * Dd + j0);
            g4.x += a.x; g4.y += a.y; g4.z += a.z; g4.w += a.w;
        }
    }
    float4 bs = *(const float4*)(bias + j0);
    float4 xv = *(const float4*)(x + row + j0);
    float4 uu = *(const float4*)(gu + row + j0);

    float sc[4], ky[4];
    const float* gg = (const float*)&g4;
    const float* gb = (const float*)&bs;
    const float* gx = (const float*)&xv;
    const float* gp = (const float*)&uu;
    #pragma unroll
    for (int e = 0; e < 4; ++e) {
        float g = gg[e] + gb[e];
        float s = (1.0f - 2.0f * gx[e]) * g * 0.5f;
        sc[e] = s;
        ky[e] = s - logf(-logf(fmaxf(gp[e], 1e-10f)));
    }
    *(float4*)(sc_ws + row + j0)  = *(const float4*)sc;
    *(float4*)(key_ws + row + j0) = *(const float4*)ky;
    *(float4*)(out + row + j0)    = xv;

    // per-chunk key argmax (chunk = 64 elems = 16 lanes), lowest-idx tie
    float kv = ky[0]; int ki = j0;
    #pragma unroll
    for (int e = 1; e < 4; ++e) if (ky[e] > kv) { kv = ky[e]; ki = j0 + e; }
    #pragma unroll
    for (int off = 1; off < 16; off <<= 1) {
        float v2 = __shfl_xor(kv, off); int i2 = __shfl_xor(ki, off);
        if (v2 > kv || (v2 == kv && i2 < ki)) { kv = v2; ki = i2; }
    }
    // per-chunk sc max + exp-sum (online-softmax partials; fixed butterfly order)
    float sm = fmaxf(fmaxf(sc[0], sc[1]), fmaxf(sc[2], sc[3]));
    #pragma unroll
    for (int off = 1; off < 16; off <<= 1) sm = fmaxf(sm, __shfl_xor(sm, off));
    float es = ((expf(sc[0] - sm) + expf(sc[1] - sm)) + expf(sc[2] - sm)) + expf(sc[3] - sm);
    #pragma unroll
    for (int off = 1; off < 16; off <<= 1) es += __shfl_xor(es, off);

    if ((tid & 15) == 0) {
        int cg = b * 64 + qd * 16 + (tid >> 4);
        kmax_ws[cg] = kv; kidx_ws[cg] = ki; smax_ws[cg] = sm; ssum_ws[cg] = es;
    }
}

// ---- Kernel 3b: per-row phase-2 (1 wave) — hierarchical tournament + accept ----
__global__ __launch_bounds__(64) void k_phase2(const float* __restrict__ x,
                                               const float* __restrict__ W,
                                               const int* __restrict__ radius_raw,
                                               const float* __restrict__ uvec,
                                               const float* __restrict__ key_ws,
                                               const float* __restrict__ sc_ws,
                                               const float* __restrict__ kmax_ws,
                                               const int* __restrict__ kidx_ws,
                                               const float* __restrict__ smax_ws,
                                               const float* __restrict__ ssum_ws,
                                               float* __restrict__ out) {
    __shared__ int   flips[MAXR];
    __shared__ float xflip[MAXR];
    const int b = blockIdx.x, lane = threadIdx.x;
    const size_t row = (size_t)b * Dd;

    // lane c owns chunk c (64 chunks/row)
    float ckmax = kmax_ws[b * 64 + lane];
    int   ckidx = kidx_ws[b * 64 + lane];
    float csmax = smax_ws[b * 64 + lane];
    float cssum = ssum_ws[b * 64 + lane];

    float mx = csmax;
    #pragma unroll
    for (int off = 1; off < 64; off <<= 1) mx = fmaxf(mx, __shfl_xor(mx, off));
    float sum_x = cssum * expf(csmax - mx);
    #pragma unroll
    for (int off = 1; off < 64; off <<= 1) sum_x += __shfl_xor(sum_x, off);
    float lse_x = mx + logf(sum_x);

    const int radius = radius_raw[b] + 1;             // [1, 15]
    unsigned rm_lo = 0, rm_hi = 0;                    // per-lane = owned chunk's removal mask
    const float* keyrow = key_ws + row;

    for (int t = 0; t < radius; ++t) {
        float v = ckmax; int i = ckidx;
        #pragma unroll
        for (int off = 1; off < 64; off <<= 1) {
            float v2 = __shfl_xor(v, off); int i2 = __shfl_xor(i, off);
            if (v2 > v || (v2 == v && i2 < i)) { v = v2; i = i2; }
        }
        const int bi = i, cw = bi >> 6;
        if (lane == 0) flips[t] = bi;
        unsigned lo = __shfl((int)rm_lo, cw), hi = __shfl((int)rm_hi, cw);
        const int bbit = bi & 63;
        if (bbit < 32) lo |= 1u << bbit; else hi |= 1u << (bbit - 32);
        // rescan winner chunk (coalesced 256 B), masked argmax for its next-best
        float kv2 = keyrow[cw * 64 + lane];
        int   id2 = cw * 64 + lane;
        bool rem = (lane < 32) ? ((lo >> lane) & 1u) : ((hi >> (lane - 32)) & 1u);
        if (rem) kv2 = -FMAX;
        #pragma unroll
        for (int off = 1; off < 64; off <<= 1) {
            float v2 = __shfl_xor(kv2, off); int i2 = __shfl_xor(id2, off);
            if (v2 > kv2 || (v2 == kv2 && i2 < id2)) { kv2 = v2; id2 = i2; }
        }
        if (lane == cw) { rm_lo = lo; rm_hi = hi; ckmax = kv2; ckidx = id2; }
    }
    __syncthreads();

    // lse_y via correction: sum_y = sum_x + sum_flips(e^{-sc-mx} - e^{+sc-mx})
    float delta = 0.0f;
    if (lane < radius) {
        int p = flips[lane];
        float sv = sc_ws[row + p];
        delta = expf(-sv - mx) - expf(sv - mx);
        xflip[lane] = x[row + p];
    }
    __syncthreads();
    float dsum = delta;
    #pragma unroll
    for (int off = 1; off < 64; off <<= 1) dsum += __shfl_xor(dsum, off);
    float lse_y = mx + logf(sum_x + dsum);

    // pair term: 0.25 * sum_{p,q in flips} d_p d_q (W_pq + W_qp)
    float ts = 0.0f;
    for (int t = lane; t < radius * radius; t += 64) {
        int p = flips[t / radius], q = flips[t % radius];
        float dp = 1.0f - 2.0f * xflip[t / radius];
        float dq = 1.0f - 2.0f * xflip[t % radius];
        ts += 0.25f * dp * dq * (W[(size_t)p * Dd + q] + W[(size_t)q * Dd + p]);
    }
    #pragma unroll
    for (int off = 1; off < 64; off <<= 1) ts += __shfl_xor(ts, off);

    float log_acc = fminf(ts + lse_x - lse_y, 0.0f);
    int accepted = (expf(log_acc) > uvec[b]) ? 1 : 0;
    if (accepted && lane < radius) {
        int p = flips[lane];
        out[row + p] = 1.0f - xflip[lane];
    }
}

extern "C" void kernel_launch(void* const* d_in, const int* in_sizes, int n_in,
                              void* d_out, int out_size, void* d_ws, size_t ws_size,
                              hipStream_t stream) {
    const float* x          = (const float*)d_in[0];
    const float* W          = (const float*)d_in[1];
    const float* bias       = (const float*)d_in[2];
    const int*   radius_raw = (const int*)d_in[3];
    const float* gu         = (const float*)d_in[4];
    const float* u          = (const float*)d_in[5];
    float* out = (float*)d_out;

    // ws layout (all 16B-aligned segments):
    // shi 33.55 | slo 33.55 | xb 2.10 | part nsplit*4.19 | key 4.19 | sc 4.19
    // | kmax 64K | kidx 64K | smax 64K | ssum 64K   (~95 MB at nsplit=4)
    unsigned short* shi = (unsigned short*)d_ws;
    unsigned short* slo = shi + (size_t)Dd * Dd;
    unsigned short* xb  = slo + (size_t)Dd * Dd;
    float* prt = (float*)(xb + (size_t)Bsz * Dd);

    const size_t fixed = (size_t)2 * Dd * Dd * 2 + (size_t)Bsz * Dd * 2;
    const size_t per_split = (size_t)Bsz * Dd * 4;
    const size_t extra = 2 * per_split + 4 * ((size_t)Bsz * 64 * 4);
    const int nsplit = (ws_size >= fixed + 4 * per_split + extra) ? 4 : 2;
    const int kchunk = Dd / nsplit;

    float* key_ws  = prt + (size_t)nsplit * Bsz * Dd;
    float* sc_ws   = key_ws + (size_t)Bsz * Dd;
    float* kmax_ws = sc_ws + (size_t)Bsz * Dd;
    int*   kidx_ws = (int*)(kmax_ws + Bsz * 64);
    float* smax_ws = (float*)(kidx_ws + Bsz * 64);
    float* ssum_ws = smax_ws + Bsz * 64;

    k_ssym<<<2080, 256, 0, stream>>>(W, x, shi, slo, xb);
    k_gemm<<<dim3(64, 4, nsplit), 128, 0, stream>>>(xb, shi, slo, prt, kchunk);
    k_phase1<<<Bsz * 4, 256, 0, stream>>>(x, gu, prt, bias, out, key_ws, sc_ws,
                                          kmax_ws, kidx_ws, smax_ws, ssum_ws, nsplit);
    k_phase2<<<Bsz, 64, 0, stream>>>(x, W, radius_raw, u, key_ws, sc_ws,
                                     kmax_ws, kidx_ws, smax_ws, ssum_ws, out);
}

// Round 15
// 170.892 us; speedup vs baseline: 1.0476x; 1.0476x over previous
//
#include <hip/hip_runtime.h>

#define Bsz 256
#define Dd  4096
#define MAXR 15
#define FMAX 3.402823466e+38f
#define BK 64
#define LSTRIDE 72              // 9 granules (odd): conflict-free phases, 16B-aligned rows

typedef short bf16x8 __attribute__((ext_vector_type(8)));
typedef float f32x4  __attribute__((ext_vector_type(4)));

__device__ __forceinline__ unsigned short f2bf(float f) {
    unsigned int u = __float_as_uint(f);
    unsigned int r = (u + 0x7fffu + ((u >> 16) & 1u)) >> 16;   // RNE
    return (unsigned short)r;
}
__device__ __forceinline__ float bf2f(unsigned short h) {
    return __uint_as_float(((unsigned int)h) << 16);
}

// ---- Kernel 1: S = 0.5*(W+W^T) -> bf16 hi/lo (triangle-paired) + fused x->bf16 ----
__global__ __launch_bounds__(256) void k_ssym(const float* __restrict__ W,
                                              const float* __restrict__ x,
                                              unsigned short* __restrict__ shi,
                                              unsigned short* __restrict__ slo,
                                              unsigned short* __restrict__ xb) {
    __shared__ float t1[64][68];
    __shared__ float t2[64][68];
    int bid = blockIdx.x;
    int bi = 0;
    while (bid >= 64 - bi) { bid -= 64 - bi; ++bi; }
    const int bj = bi + bid;
    const int i0 = bi * 64, j0 = bj * 64;
    const int tid = threadIdx.x;

    #pragma unroll
    for (int sb = 0; sb < 4; ++sb) {
        int s = sb * 256 + tid;
        int r = s >> 4, q = (s & 15) * 4;
        *(float4*)&t1[r][q] = *(const float4*)(W + (size_t)(i0 + r) * Dd + j0 + q);
        *(float4*)&t2[r][q] = *(const float4*)(W + (size_t)(j0 + r) * Dd + i0 + q);
    }
    __syncthreads();

    const int r = tid >> 2, c0 = (tid & 3) * 16;
    {   // S_ij[r][c] = 0.5*(t1[r][c] + t2[c][r])
        unsigned short vh[16], vl[16];
        #pragma unroll
        for (int k = 0; k < 16; ++k) {
            float s = 0.5f * (t1[r][c0 + k] + t2[c0 + k][r]);
            vh[k] = f2bf(s);
            vl[k] = f2bf(s - bf2f(vh[k]));
        }
        size_t o = (size_t)(i0 + r) * Dd + j0 + c0;
        *(uint4*)(shi + o) = *(const uint4*)&vh[0];
        *(uint4*)(shi + o + 8) = *(const uint4*)&vh[8];
        *(uint4*)(slo + o) = *(const uint4*)&vl[0];
        *(uint4*)(slo + o + 8) = *(const uint4*)&vl[8];
    }
    if (bi != bj) {   // S_ji[r][c] = 0.5*(t2[r][c] + t1[c][r])
        unsigned short vh[16], vl[16];
        #pragma unroll
        for (int k = 0; k < 16; ++k) {
            float s = 0.5f * (t2[r][c0 + k] + t1[c0 + k][r]);
            vh[k] = f2bf(s);
            vl[k] = f2bf(s - bf2f(vh[k]));
        }
        size_t o = (size_t)(j0 + r) * Dd + i0 + c0;
        *(uint4*)(shi + o) = *(const uint4*)&vh[0];
        *(uint4*)(shi + o + 8) = *(const uint4*)&vh[8];
        *(uint4*)(slo + o) = *(const uint4*)&vl[0];
        *(uint4*)(slo + o + 8) = *(const uint4*)&vl[8];
    }

    if (blockIdx.x < 256) {
        const float* xp = x + (size_t)blockIdx.x * 4096;
        unsigned short* xo = xb + (size_t)blockIdx.x * 4096;
        #pragma unroll
        for (int c = 0; c < 4; ++c) {
            int e = c * 1024 + tid * 4;
            float4 v = *(const float4*)(xp + e);
            unsigned short o4[4] = { f2bf(v.x), f2bf(v.y), f2bf(v.z), f2bf(v.w) };
            *(uint2*)(xo + e) = *(const uint2*)o4;
        }
    }
}

// ---- Kernel 2: part[z] = X @ S(K-chunk z); single-buffer + VGPR prefetch ----
__global__ __launch_bounds__(128) void k_gemm(const unsigned short* __restrict__ xb,
                                              const unsigned short* __restrict__ shi,
                                              const unsigned short* __restrict__ slo,
                                              float* __restrict__ part,
                                              int kchunk) {
    __shared__ __align__(16) unsigned short As[64 * LSTRIDE];
    __shared__ __align__(16) unsigned short Bh[64 * LSTRIDE];
    __shared__ __align__(16) unsigned short Bl[64 * LSTRIDE];
    const int tid = threadIdx.x;
    const int n0 = blockIdx.x * 64, m0 = blockIdx.y * 64;
    const int kbase = blockIdx.z * kchunk;
    const int w = tid >> 6, lane = tid & 63;
    const int ln = lane & 15, quad = lane >> 4;

    unsigned ga[4], gb[4];
    int lofs[4];
    #pragma unroll
    for (int j = 0; j < 4; ++j) {
        int s = tid + j * 128;
        int r = s >> 3, g = s & 7;
        ga[j]   = (unsigned)((m0 + r) * Dd + kbase + g * 8);
        gb[j]   = (unsigned)((n0 + r) * Dd + kbase + g * 8);
        lofs[j] = r * LSTRIDE + g * 8;
    }

    f32x4 acc[4][2];
    #pragma unroll
    for (int mt = 0; mt < 4; ++mt)
        #pragma unroll
        for (int ct = 0; ct < 2; ++ct)
            #pragma unroll
            for (int rr = 0; rr < 4; ++rr) acc[mt][ct][rr] = 0.0f;

    bf16x8 va[4], vh[4], vl[4];
    #pragma unroll
    for (int j = 0; j < 4; ++j) {
        va[j] = *(const bf16x8*)(xb  + ga[j]);
        vh[j] = *(const bf16x8*)(shi + gb[j]);
        vl[j] = *(const bf16x8*)(slo + gb[j]);
    }

    for (int k0 = 0; k0 < kchunk; k0 += BK) {
        __syncthreads();
        #pragma unroll
        for (int j = 0; j < 4; ++j) {
            *(bf16x8*)&As[lofs[j]] = va[j];
            *(bf16x8*)&Bh[lofs[j]] = vh[j];
            *(bf16x8*)&Bl[lofs[j]] = vl[j];
        }
        {
            int kn = k0 + BK;
            int ks = (kn < kchunk) ? kn : 0;
            #pragma unroll
            for (int j = 0; j < 4; ++j) {
                va[j] = *(const bf16x8*)(xb  + ga[j] + ks);
                vh[j] = *(const bf16x8*)(shi + gb[j] + ks);
                vl[j] = *(const bf16x8*)(slo + gb[j] + ks);
            }
        }
        __syncthreads();
        #pragma unroll
        for (int kk = 0; kk < BK; kk += 32) {
            const int gr = (kk >> 3) + quad;
            bf16x8 a[4];
            #pragma unroll
            for (int mt = 0; mt < 4; ++mt)
                a[mt] = *(const bf16x8*)&As[(mt * 16 + ln) * LSTRIDE + gr * 8];
            #pragma unroll
            for (int ct = 0; ct < 2; ++ct) {
                int rb = w * 32 + ct * 16 + ln;
                bf16x8 bh = *(const bf16x8*)&Bh[rb * LSTRIDE + gr * 8];
                bf16x8 bl = *(const bf16x8*)&Bl[rb * LSTRIDE + gr * 8];
                #pragma unroll
                for (int mt = 0; mt < 4; ++mt) {
                    acc[mt][ct] = __builtin_amdgcn_mfma_f32_16x16x32_bf16(a[mt], bh, acc[mt][ct], 0, 0, 0);
                    acc[mt][ct] = __builtin_amdgcn_mfma_f32_16x16x32_bf16(a[mt], bl, acc[mt][ct], 0, 0, 0);
                }
            }
        }
    }
    float* prow = part + (size_t)blockIdx.z * (Bsz * Dd);
    #pragma unroll
    for (int mt = 0; mt < 4; ++mt)
        #pragma unroll
        for (int ct = 0; ct < 2; ++ct)
            #pragma unroll
            for (int rr = 0; rr < 4; ++rr) {
                int m = m0 + mt * 16 + quad * 4 + rr;
                int n = n0 + w * 32 + ct * 16 + ln;
                prow[(size_t)m * Dd + n] = acc[mt][ct][rr];
            }
}

// ---------------- block reduction helpers (256 threads = 4 waves) ----------------
__device__ __forceinline__ float block_max256(float v, float* redf) {
    #pragma unroll
    for (int off = 32; off; off >>= 1) v = fmaxf(v, __shfl_down(v, off));
    __syncthreads();
    if ((threadIdx.x & 63) == 0) redf[threadIdx.x >> 6] = v;
    __syncthreads();
    return fmaxf(fmaxf(redf[0], redf[1]), fmaxf(redf[2], redf[3]));
}
__device__ __forceinline__ float block_sum256(float v, float* redf) {
    #pragma unroll
    for (int off = 32; off; off >>= 1) v += __shfl_down(v, off);
    __syncthreads();
    if ((threadIdx.x & 63) == 0) redf[threadIdx.x >> 6] = v;
    __syncthreads();
    return (redf[0] + redf[1]) + (redf[2] + redf[3]);    // fixed order: deterministic
}

// ---- Kernel 3: per-row epilogue; launch_bounds(256,1) frees the VGPR budget ----
__global__ __launch_bounds__(256, 1) void k_epilogue(const float* __restrict__ x,
                                                  const float* __restrict__ W,
                                                  const int* __restrict__ radius_raw,
                                                  const float* __restrict__ gu,
                                                  const float* __restrict__ uvec,
                                                  const float* __restrict__ part,
                                                  const float* __restrict__ bias,
                                                  float* __restrict__ out,
                                                  int nsplit) {
    __shared__ float scx_s[Dd];        // 16 KB: sc values for flip-position lookups
    __shared__ float redf[2][4];       // double-buffered argmax combine
    __shared__ int   redi[2][4];
    __shared__ float redsum[4];
    __shared__ int   flips[MAXR];

    const int b = blockIdx.x;
    const int tid = threadIdx.x;
    const float* xrow  = x  + (size_t)b * Dd;
    const float* gurow = gu + (size_t)b * Dd;

    // ---- phase 1: grad = sum_z part[z] + bias (fixed order); sc/key in registers ----
    float4 g4[4], bs4[4], xv4[4], uu4[4];
    #pragma unroll
    for (int c = 0; c < 4; ++c) {
        int j = c * 1024 + tid * 4;
        g4[c]  = *(const float4*)(part + (size_t)b * Dd + j);      // z = 0
        bs4[c] = *(const float4*)(bias + j);
        xv4[c] = *(const float4*)(xrow + j);
        uu4[c] = *(const float4*)(gurow + j);
    }
    if (nsplit == 4) {
        // hand-unrolled: all 12 loads issue as one batch; add order ((p0+p1)+p2)+p3
        float4 p1[4], p2[4], p3[4];
        #pragma unroll
        for (int c = 0; c < 4; ++c) {
            int j = c * 1024 + tid * 4;
            p1[c] = *(const float4*)(part + (size_t)(1 * Bsz + b) * Dd + j);
            p2[c] = *(const float4*)(part + (size_t)(2 * Bsz + b) * Dd + j);
            p3[c] = *(const float4*)(part + (size_t)(3 * Bsz + b) * Dd + j);
        }
        #pragma unroll
        for (int c = 0; c < 4; ++c) {
            g4[c].x = ((g4[c].x + p1[c].x) + p2[c].x) + p3[c].x;
            g4[c].y = ((g4[c].y + p1[c].y) + p2[c].y) + p3[c].y;
            g4[c].z = ((g4[c].z + p1[c].z) + p2[c].z) + p3[c].z;
            g4[c].w = ((g4[c].w + p1[c].w) + p2[c].w) + p3[c].w;
        }
    } else {
        for (int z = 1; z < nsplit; ++z) {
            const float* pz = part + (size_t)z * (Bsz * Dd) + (size_t)b * Dd;
            #pragma unroll
            for (int c = 0; c < 4; ++c) {
                float4 a = *(const float4*)(pz + c * 1024 + tid * 4);
                g4[c].x += a.x; g4[c].y += a.y; g4[c].z += a.z; g4[c].w += a.w;
            }
        }
    }
    float sc[16], ky[16];
    float lmax = -FMAX;
    float lkey = -FMAX; int lidx = 0x7fffffff;
    #pragma unroll
    for (int c = 0; c < 4; ++c) {
        const float* gg = (const float*)&g4[c];
        const float* gc = (const float*)&bs4[c];
        const float* gx = (const float*)&xv4[c];
        const float* gup = (const float*)&uu4[c];
        #pragma unroll
        for (int e = 0; e < 4; ++e) {
            int r = c * 4 + e;
            float g = gg[e] + gc[e];
            float s = (1.0f - 2.0f * gx[e]) * g * 0.5f;
            float k = s - logf(-logf(fmaxf(gup[e], 1e-10f)));
            sc[r] = s;
            ky[r] = k;
            lmax = fmaxf(lmax, s);
            if (k > lkey) { lkey = k; lidx = c * 1024 + tid * 4 + e; }  // incr j: lowest-idx tie
        }
        *(float4*)&scx_s[c * 1024 + tid * 4] = *(const float4*)&sc[c * 4];
    }

    // ---- lse_x ----
    float mx = block_max256(lmax, redsum);
    float ls = 0.0f;
    #pragma unroll
    for (int r = 0; r < 16; ++r) ls += expf(sc[r] - mx);
    float sum_x = block_sum256(ls, redsum);
    float lse_x = mx + logf(sum_x);

    // ---- top-radius: tournament over register-cached per-thread maxima ----
    const int radius = radius_raw[b] + 1;             // [1, 15]
    unsigned removed = 0;
    for (int t = 0; t < radius; ++t) {
        float v = lkey; int idx = lidx;
        #pragma unroll
        for (int off = 32; off; off >>= 1) {
            float v2 = __shfl_down(v, off);
            int   i2 = __shfl_down(idx, off);
            if (v2 > v || (v2 == v && i2 < idx)) { v = v2; idx = i2; }
        }
        const int buf = t & 1;
        if ((tid & 63) == 0) { redf[buf][tid >> 6] = v; redi[buf][tid >> 6] = idx; }
        __syncthreads();
        float bv = redf[buf][0]; int bi = redi[buf][0];
        #pragma unroll
        for (int w2 = 1; w2 < 4; ++w2) {
            float v2 = redf[buf][w2]; int i2 = redi[buf][w2];
            if (v2 > bv || (v2 == bv && i2 < bi)) { bv = v2; bi = i2; }
        }
        if (tid == ((bi >> 2) & 255)) {       // owner: remove + rescan registers
            removed |= 1u << (((bi >> 10) << 2) | (bi & 3));
            lkey = -FMAX; lidx = 0x7fffffff;
            #pragma unroll
            for (int c = 0; c < 4; ++c)
                #pragma unroll
                for (int e = 0; e < 4; ++e) {
                    int r = c * 4 + e;
                    if (!(removed & (1u << r)) && ky[r] > lkey) {
                        lkey = ky[r]; lidx = c * 1024 + tid * 4 + e;
                    }
                }
        }
        if (tid == 0) flips[t] = bi;
    }
    __syncthreads();                           // flips[] visible to all

    // ---- lse_y via correction: sum_y = sum_x + sum_flips(e^{-sc-mx} - e^{+sc-mx}) ----
    float delta = 0.0f;
    if (tid < radius) {
        float sv = scx_s[flips[tid]];
        delta = expf(-sv - mx) - expf(sv - mx);
    }
    float sum_y = sum_x + block_sum256(delta, redsum);
    float lse_y = mx + logf(sum_y);

    // ---- pair term: 0.25 * sum_{p,q in flips} d_p d_q (W_pq + W_qp) ----
    float ts = 0.0f;
    for (int t = tid; t < radius * radius; t += 256) {
        int p = flips[t / radius], q = flips[t % radius];
        float dp = 1.0f - 2.0f * xrow[p];
        float dq = 1.0f - 2.0f * xrow[q];
        ts += 0.25f * dp * dq * (W[(size_t)p * Dd + q] + W[(size_t)q * Dd + p]);
    }
    float T = block_sum256(ts, redsum);

    float log_acc = fminf(T + lse_x - lse_y, 0.0f);
    int accepted = (expf(log_acc) > uvec[b]) ? 1 : 0;

    // ---- output: x everywhere (from registers), flips overwritten iff accepted ----
    float* orow = out + (size_t)b * Dd;
    #pragma unroll
    for (int c = 0; c < 4; ++c)
        *(float4*)(orow + c * 1024 + tid * 4) = xv4[c];
    __syncthreads();
    if (accepted && tid < radius) {
        int p = flips[tid];
        orow[p] = 1.0f - xrow[p];
    }
}

extern "C" void kernel_launch(void* const* d_in, const int* in_sizes, int n_in,
                              void* d_out, int out_size, void* d_ws, size_t ws_size,
                              hipStream_t stream) {
    const float* x          = (const float*)d_in[0];
    const float* W          = (const float*)d_in[1];
    const float* bias       = (const float*)d_in[2];
    const int*   radius_raw = (const int*)d_in[3];
    const float* gu         = (const float*)d_in[4];
    const float* u          = (const float*)d_in[5];
    float* out = (float*)d_out;

    // ws: shi 33.55 MB | slo 33.55 MB | xb 2.1 MB | part nsplit*4.19 MB
    unsigned short* shi = (unsigned short*)d_ws;
    unsigned short* slo = shi + (size_t)Dd * Dd;
    unsigned short* xb  = slo + (size_t)Dd * Dd;
    float*          prt = (float*)(xb + (size_t)Bsz * Dd);

    // nsplit=4 (r8/r12/r13 champion config); ws_size constant across calls => graph-safe.
    const size_t fixed = (size_t)2 * Dd * Dd * 2 + (size_t)Bsz * Dd * 2;
    const int nsplit = (ws_size >= fixed + (size_t)4 * Bsz * Dd * 4) ? 4 : 2;
    const int kchunk = Dd / nsplit;

    k_ssym<<<2080, 256, 0, stream>>>(W, x, shi, slo, xb);
    k_gemm<<<dim3(64, 4, nsplit), 128, 0, stream>>>(xb, shi, slo, prt, kchunk);
    k_epilogue<<<Bsz, 256, 0, stream>>>(x, W, radius_raw, gu, u, prt, bias, out, nsplit);
}